// Round 1
// baseline (433.697 us; speedup 1.0000x reference)
//
#include <hip/hip_runtime.h>
#include <stdint.h>

#define B 8
#define F 8192
#define C 256
#define K 4
#define P (F / 4)   // 2048

// ---------------------------------------------------------------------------
// Kernel W: one wave (64 lanes) per face.
//  - gather 4 ring rows, mean over K, squared-norm partial, wave-reduce, sqrt
//  - copy features row -> out row (out doubles as the scat accumulator)
//  - zero cnt, zero flag
// ---------------------------------------------------------------------------
__global__ __launch_bounds__(256) void kW(const float* __restrict__ feat,
                                          const int* __restrict__ ring,
                                          float* __restrict__ out,
                                          float* __restrict__ w,
                                          float* __restrict__ cnt,
                                          int* __restrict__ flag) {
    const int wid  = blockIdx.x * 4 + (threadIdx.x >> 6);  // face_lin in [0, B*F)
    const int lane = threadIdx.x & 63;
    const int b    = wid >> 13;                            // / F (F = 8192)

    float4 acc = make_float4(0.f, 0.f, 0.f, 0.f);
    const int rbase = wid * K;
#pragma unroll
    for (int k = 0; k < K; ++k) {
        const int r = ring[rbase + k];
        const float4* src = (const float4*)(feat + ((size_t)(b * F + r) * C));
        float4 v = src[lane];                              // 16B/lane, coalesced row
        acc.x += v.x; acc.y += v.y; acc.z += v.z; acc.w += v.w;
    }
    // mean = acc * 0.25 ; partial sum of squares = (acc . acc) * 0.0625
    float s = (acc.x * acc.x + acc.y * acc.y + acc.z * acc.z + acc.w * acc.w) * 0.0625f;
#pragma unroll
    for (int off = 32; off > 0; off >>= 1) s += __shfl_down(s, off, 64);
    if (lane == 0) {
        w[wid]    = sqrtf(s);
        cnt[wid]  = 0.0f;
        flag[wid] = 0;
    }
    // copy this face's row into out (scat accumulator base value = features)
    const float4* srow = (const float4*)(feat + (size_t)wid * C);
    float4*       drow = (float4*)(out + (size_t)wid * C);
    drow[lane] = srow[lane];
}

// ---------------------------------------------------------------------------
// Kernel S: per-batch bitonic sort of (w_bits << 32 | idx) in LDS (64 KiB).
// First P sorted keys = the P smallest-w faces, ties broken by lower index
// (matches jax.lax.top_k(-w, P) selection exactly).
// ---------------------------------------------------------------------------
__global__ __launch_bounds__(1024) void kS(const float* __restrict__ w,
                                           int* __restrict__ flag,
                                           int* __restrict__ list) {
    __shared__ uint64_t keys[F];                           // 8192 * 8B = 64 KiB
    const int b   = blockIdx.x;
    const int tid = threadIdx.x;

    for (int i = tid; i < F; i += 1024) {
        const uint32_t bits = __float_as_uint(w[b * F + i]);  // w >= 0: monotonic
        keys[i] = ((uint64_t)bits << 32) | (uint32_t)i;
    }
    __syncthreads();

    for (int k = 2; k <= F; k <<= 1) {
        for (int j = k >> 1; j > 0; j >>= 1) {
            for (int i = tid; i < F; i += 1024) {
                const int ixj = i ^ j;
                if (ixj > i) {
                    const uint64_t a = keys[i];
                    const uint64_t c = keys[ixj];
                    const bool up = ((i & k) == 0);
                    if ((a > c) == up) { keys[i] = c; keys[ixj] = a; }
                }
            }
            __syncthreads();
        }
    }

    for (int s = tid; s < P; s += 1024) {
        const uint32_t idx = (uint32_t)keys[s];
        flag[b * F + idx] = 1;
        list[b * P + s]   = (int)idx;
    }
}

// ---------------------------------------------------------------------------
// Kernel C: one wave per (b, p, j) — scatter cf/3 into neighbor row via
// fp32 atomics (accumulating on top of the features copy in d_out), and one
// cnt increment per (p, j).
// ---------------------------------------------------------------------------
__global__ __launch_bounds__(256) void kC(const float* __restrict__ feat,
                                          const int* __restrict__ adj,
                                          const int* __restrict__ list,
                                          float* __restrict__ out,
                                          float* __restrict__ cnt) {
    const int gwid = blockIdx.x * 4 + (threadIdx.x >> 6);  // [0, B*P*3)
    const int lane = threadIdx.x & 63;
    const int j  = gwid % 3;
    const int bp = gwid / 3;                               // [0, B*P)
    const int b  = bp / P;

    const int idx = list[bp];
    const int n   = adj[((size_t)(b * F) + idx) * 3 + j];

    const float4* src = (const float4*)(feat + (size_t)(b * F + idx) * C);
    float*        dst = out + (size_t)(b * F + n) * C;

    const float4 v = src[lane];
    const float inv3 = 1.0f / 3.0f;
    const int c0 = lane * 4;
    atomicAdd(dst + c0 + 0, v.x * inv3);
    atomicAdd(dst + c0 + 1, v.y * inv3);
    atomicAdd(dst + c0 + 2, v.z * inv3);
    atomicAdd(dst + c0 + 3, v.w * inv3);
    if (lane == 0) atomicAdd(&cnt[b * F + n], 1.0f);
}

// ---------------------------------------------------------------------------
// Kernel F: out = flag ? 0 : out / (1 + cnt)     (one float4 per thread)
// ---------------------------------------------------------------------------
__global__ __launch_bounds__(256) void kF(float* __restrict__ out,
                                          const float* __restrict__ cnt,
                                          const int* __restrict__ flag) {
    const size_t g    = (size_t)blockIdx.x * 256 + threadIdx.x;  // float4 index
    const size_t face = g >> 6;                                  // / (C/4)
    float4* p = (float4*)out + g;
    float4 v = *p;
    if (flag[face]) {
        v = make_float4(0.f, 0.f, 0.f, 0.f);
    } else {
        const float inv = 1.0f / (1.0f + cnt[face]);
        v.x *= inv; v.y *= inv; v.z *= inv; v.w *= inv;
    }
    *p = v;
}

extern "C" void kernel_launch(void* const* d_in, const int* in_sizes, int n_in,
                              void* d_out, int out_size, void* d_ws, size_t ws_size,
                              hipStream_t stream) {
    const float* feat = (const float*)d_in[0];
    const int*   adj  = (const int*)d_in[1];
    const int*   ring = (const int*)d_in[2];
    float* out = (float*)d_out;

    float* w    = (float*)d_ws;        // B*F floats
    float* cnt  = w + B * F;           // B*F floats
    int*   flag = (int*)(cnt + B * F); // B*F ints
    int*   list = flag + B * F;        // B*P ints

    kW<<<(B * F) / 4, 256, 0, stream>>>(feat, ring, out, w, cnt, flag);
    kS<<<B, 1024, 0, stream>>>(w, flag, list);
    kC<<<(B * P * 3) / 4, 256, 0, stream>>>(feat, adj, list, out, cnt);
    kF<<<(B * F * C / 4) / 256, 256, 0, stream>>>(out, cnt, flag);
}

// Round 2
// 267.022 us; speedup vs baseline: 1.6242x; 1.6242x over previous
//
#include <hip/hip_runtime.h>
#include <stdint.h>

#define B 8
#define F 8192
#define C 256
#define K 4
#define P (F / 4)   // 2048
#define CAP 16      // max incoming collapsed faces tracked per target face

// ---------------------------------------------------------------------------
// Kernel W: one wave per face — ring gather, mean over K, L2 norm.
// Also zeroes cnt/flag for the later stages.
// ---------------------------------------------------------------------------
__global__ __launch_bounds__(256) void kW(const float* __restrict__ feat,
                                          const int* __restrict__ ring,
                                          float* __restrict__ w,
                                          int* __restrict__ cnt,
                                          int* __restrict__ flag) {
    const int wid  = blockIdx.x * 4 + (threadIdx.x >> 6);  // face_lin in [0, B*F)
    const int lane = threadIdx.x & 63;
    const int b    = wid >> 13;                            // / F

    float4 acc = make_float4(0.f, 0.f, 0.f, 0.f);
    const int rbase = wid * K;
#pragma unroll
    for (int k = 0; k < K; ++k) {
        const int r = ring[rbase + k];
        const float4 v = ((const float4*)(feat + (size_t)(b * F + r) * C))[lane];
        acc.x += v.x; acc.y += v.y; acc.z += v.z; acc.w += v.w;
    }
    float s = (acc.x * acc.x + acc.y * acc.y + acc.z * acc.z + acc.w * acc.w) * 0.0625f;
#pragma unroll
    for (int off = 32; off > 0; off >>= 1) s += __shfl_down(s, off, 64);
    if (lane == 0) {
        w[wid]    = sqrtf(s);
        cnt[wid]  = 0;
        flag[wid] = 0;
    }
}

// ---------------------------------------------------------------------------
// Kernel S: per-batch bitonic sort of (w_bits << 32 | idx) in 64 KiB LDS.
// First P keys = exact P smallest (ties by lower idx) -> set flag.
// ---------------------------------------------------------------------------
__global__ __launch_bounds__(1024) void kS(const float* __restrict__ w,
                                           int* __restrict__ flag) {
    __shared__ uint64_t keys[F];                           // 64 KiB
    const int b   = blockIdx.x;
    const int tid = threadIdx.x;

    for (int i = tid; i < F; i += 1024) {
        const uint32_t bits = __float_as_uint(w[b * F + i]);  // w >= 0: monotonic
        keys[i] = ((uint64_t)bits << 32) | (uint32_t)i;
    }
    __syncthreads();

    for (int k = 2; k <= F; k <<= 1) {
        for (int j = k >> 1; j > 0; j >>= 1) {
            for (int i = tid; i < F; i += 1024) {
                const int ixj = i ^ j;
                if (ixj > i) {
                    const uint64_t a = keys[i];
                    const uint64_t c = keys[ixj];
                    const bool up = ((i & k) == 0);
                    if ((a > c) == up) { keys[i] = c; keys[ixj] = a; }
                }
            }
            __syncthreads();
        }
    }

    for (int s = tid; s < P; s += 1024) {
        const uint32_t idx = (uint32_t)keys[s];
        flag[b * F + idx] = 1;
    }
}

// ---------------------------------------------------------------------------
// Kernel L: build per-target incoming lists. One thread per face; flagged
// faces push their linear index into each of their 3 adjacency targets.
// 49K int atomics total (vs 12.6M fp32 atomics in the scatter version).
// ---------------------------------------------------------------------------
__global__ __launch_bounds__(256) void kL(const int* __restrict__ adj,
                                          const int* __restrict__ flag,
                                          int* __restrict__ cnt,
                                          int* __restrict__ srcs) {
    const int t = blockIdx.x * 256 + threadIdx.x;          // linear face [0, B*F)
    if (!flag[t]) return;
    const int b = t >> 13;
#pragma unroll
    for (int j = 0; j < 3; ++j) {
        const int n   = adj[(size_t)t * 3 + j];
        const int tgt = b * F + n;
        const int slot = atomicAdd(&cnt[tgt], 1);
        if (slot < CAP) srcs[(size_t)tgt * CAP + slot] = t;
    }
}

// ---------------------------------------------------------------------------
// Kernel G: one wave per face — fused merge + normalize + erase.
//   flagged: out row = 0
//   else:    out = (feat[f] + sum_in feat[s]/3) / (1 + cnt[f])
// flag/cnt are wave-uniform (one face per wave) -> no divergence.
// ---------------------------------------------------------------------------
__global__ __launch_bounds__(256) void kG(const float* __restrict__ feat,
                                          const int* __restrict__ cnt,
                                          const int* __restrict__ flag,
                                          const int* __restrict__ srcs,
                                          float* __restrict__ out) {
    const int wid  = blockIdx.x * 4 + (threadIdx.x >> 6);
    const int lane = threadIdx.x & 63;
    float4* drow = (float4*)(out + (size_t)wid * C);

    if (flag[wid]) {
        drow[lane] = make_float4(0.f, 0.f, 0.f, 0.f);
        return;
    }
    const int m  = cnt[wid];
    const int mm = m < CAP ? m : CAP;

    float4 acc = ((const float4*)(feat + (size_t)wid * C))[lane];
    const float inv3 = 1.0f / 3.0f;
    for (int i = 0; i < mm; ++i) {
        const int s = srcs[(size_t)wid * CAP + i];
        const float4 v = ((const float4*)(feat + (size_t)s * C))[lane];
        acc.x += v.x * inv3; acc.y += v.y * inv3;
        acc.z += v.z * inv3; acc.w += v.w * inv3;
    }
    const float inv = 1.0f / (1.0f + (float)m);
    acc.x *= inv; acc.y *= inv; acc.z *= inv; acc.w *= inv;
    drow[lane] = acc;
}

extern "C" void kernel_launch(void* const* d_in, const int* in_sizes, int n_in,
                              void* d_out, int out_size, void* d_ws, size_t ws_size,
                              hipStream_t stream) {
    const float* feat = (const float*)d_in[0];
    const int*   adj  = (const int*)d_in[1];
    const int*   ring = (const int*)d_in[2];
    float* out = (float*)d_out;

    float* w    = (float*)d_ws;          // B*F floats
    int*   cnt  = (int*)(w + B * F);     // B*F ints
    int*   flag = cnt + B * F;           // B*F ints
    int*   srcs = flag + B * F;          // B*F*CAP ints (4 MiB)

    kW<<<(B * F) / 4, 256, 0, stream>>>(feat, ring, w, cnt, flag);
    kS<<<B, 1024, 0, stream>>>(w, flag);
    kL<<<(B * F) / 256, 256, 0, stream>>>(adj, flag, cnt, srcs);
    kG<<<(B * F) / 4, 256, 0, stream>>>(feat, cnt, flag, srcs, out);
}